// Round 7
// baseline (434.565 us; speedup 1.0000x reference)
//
#include <hip/hip_runtime.h>

#define PPB   128
#define NZ    8
#define INC   64
#define OUTC  128
#define NB    4
#define HH    256
#define WWD   256
#define HWD   (HH * WWD)
#define NSEG  (NB * HH)        // 1024 full-row segments: seg = b*HH + h

__device__ __forceinline__ unsigned bf16_rne(float x) {
    unsigned u = __float_as_uint(x);
    return (u + 0x7FFFu + ((u >> 16) & 1u)) >> 16;
}
__device__ __forceinline__ unsigned pack2(float e, float o) {   // (even ch, odd ch)
    return bf16_rne(e) | (bf16_rne(o) << 16);
}
// LDS channel swizzle: bijective in cc for fixed w; bank = ((cc>>1)+w)%32
__device__ __forceinline__ int swz(int cc, int w) {
    return ((cc & 1) << 5) | (((cc >> 1) + w) & 31);
}

// ---------------- pass 1: histograms (z bins + row segments) ----------------
__global__ void hist_kernel(const int* __restrict__ z_idx, const int* __restrict__ batch_idx,
                            const int* __restrict__ d0_idx,
                            int* __restrict__ counts, int* __restrict__ seghist, int n) {
    __shared__ int lc[NZ];
    int t = threadIdx.x;
    if (t < NZ) lc[t] = 0;
    __syncthreads();
    int i = blockIdx.x * blockDim.x + t;
    if (i < n) {
        int z = z_idx[i]; z = z < 0 ? 0 : (z > NZ - 1 ? NZ - 1 : z);
        atomicAdd(&lc[z], 1);
        atomicAdd(&seghist[batch_idx[i] * HH + d0_idx[i]], 1);
    }
    __syncthreads();
    if (t < NZ && lc[t] > 0) atomicAdd(&counts[t], lc[t]);
}

// ---------------- pass 2: prefixes (z padded; segment exclusive scan over 1024) ----------------
__global__ void prefix_kernel(const int* __restrict__ counts, int* __restrict__ pstart,
                              const int* __restrict__ seghist, int* __restrict__ segstart) {
    __shared__ int part[256];
    int t = threadIdx.x;
    if (t == 0) {
        int off = 0;
        for (int z = 0; z < NZ; ++z) {
            pstart[z] = off;
            off += ((counts[z] + PPB - 1) / PPB) * PPB;
        }
        pstart[NZ] = off;
    }
    int loc[4]; int s = 0;
#pragma unroll
    for (int j = 0; j < 4; ++j) { loc[j] = seghist[t * 4 + j]; s += loc[j]; }
    part[t] = s;
    __syncthreads();
    for (int d = 1; d < 256; d <<= 1) {
        int v = (t >= d) ? part[t - d] : 0;
        __syncthreads();
        part[t] += v;
        __syncthreads();
    }
    int excl = part[t] - s;
#pragma unroll
    for (int j = 0; j < 4; ++j) { segstart[t * 4 + j] = excl; excl += loc[j]; }
    if (t == 255) segstart[NSEG] = excl;
}

// ---------------- pass 3: scatter ids into z bins + segment-ordered positions ----------------
__global__ void scatter_kernel(const int* __restrict__ z_idx, const int* __restrict__ batch_idx,
                               const int* __restrict__ d0_idx, const int* __restrict__ d1_idx,
                               const int* __restrict__ pstart, int* __restrict__ cursors,
                               const int* __restrict__ segstart, int* __restrict__ segcur,
                               int* __restrict__ bins, int* __restrict__ segpos,
                               unsigned short* __restrict__ wlist, int n) {
    __shared__ int lc[NZ];
    __shared__ int lbase[NZ];
    int t = threadIdx.x;
    if (t < NZ) lc[t] = 0;
    __syncthreads();
    int i = blockIdx.x * blockDim.x + t;
    int z = 0, rank = 0;
    bool valid = (i < n);
    if (valid) {
        z = z_idx[i]; z = z < 0 ? 0 : (z > NZ - 1 ? NZ - 1 : z);
        rank = atomicAdd(&lc[z], 1);
    }
    __syncthreads();
    if (t < NZ) lbase[t] = (lc[t] > 0) ? atomicAdd(&cursors[t], lc[t]) : 0;
    __syncthreads();
    if (valid) {
        int slot = pstart[z] + lbase[z] + rank;
        bins[slot] = i;
        int seg = batch_idx[i] * HH + d0_idx[i];
        int r2 = atomicAdd(&segcur[seg], 1);
        int sp = segstart[seg] + r2;
        segpos[slot] = 1 + sp;               // row 0 of bevf = dump for padding
        wlist[sp] = (unsigned short)d1_idx[i];
    }
}

// ---------------- pass 4: LDS-tiled fp32 GEMM per z-bin -> bf16 rows at segment-ordered pos ----------------
// Row layout: dword d packs channels (2d, 2d+1); dwords 0..31 = ch 0..63, 32..63 = ch 64..127.
__global__ __launch_bounds__(256) void gemm_kernel(
        const float* __restrict__ features, const float* __restrict__ kw,
        const float* __restrict__ bias,
        const int* __restrict__ pstart, const int* __restrict__ bins,
        const int* __restrict__ segpos, unsigned* __restrict__ bevf) {
    __shared__ __align__(16) float A[INC][PPB];     // 32 KiB, [k][p]
    __shared__ __align__(16) float Wl[INC][OUTC];   // 32 KiB, [k][c]

    int start = blockIdx.x * PPB;
    int total = pstart[NZ];
    if (start >= total) return;
    int z = 0;
#pragma unroll
    for (int zz = 1; zz < NZ; ++zz)
        if (start >= pstart[zz]) z = zz;

    int tid = threadIdx.x;
    int tc = tid & 15;
    int tp = tid >> 4;
    int p0 = tp * 8;

    int posArr[8];
#pragma unroll
    for (int i = 0; i < 8; ++i) posArr[i] = segpos[start + p0 + i];

    {   // stage W[z]: straight 32KB copy
        const float4* src = (const float4*)(kw + (size_t)z * INC * OUTC);
        float4* dst = (float4*)&Wl[0][0];
#pragma unroll
        for (int i = 0; i < 8; ++i) dst[tid + 256 * i] = src[tid + 256 * i];
    }
    {   // stage A: gather 128 feature rows, write transposed [k][p]
        int r = tid >> 1;
        int half = tid & 1;
        int raw = bins[start + r];
        int nid = raw < 0 ? 0 : raw;
        const float4* fp = (const float4*)(features + (size_t)nid * INC) + half * 8;
#pragma unroll
        for (int q = 0; q < 8; ++q) {
            float4 f = fp[q];
            int k = half * 32 + q * 4;
            A[k + 0][r] = f.x; A[k + 1][r] = f.y; A[k + 2][r] = f.z; A[k + 3][r] = f.w;
        }
    }
    __syncthreads();

    int cl = tc * 4;
    int chh = 64 + cl;

    float acc[8][8];
#pragma unroll
    for (int i = 0; i < 8; ++i)
#pragma unroll
        for (int j = 0; j < 8; ++j) acc[i][j] = 0.f;

#pragma unroll 4
    for (int k = 0; k < INC; ++k) {
        float4 b0 = *(const float4*)&Wl[k][cl];
        float4 b1 = *(const float4*)&Wl[k][chh];
        float4 a0 = *(const float4*)&A[k][p0];
        float4 a1 = *(const float4*)&A[k][p0 + 4];
        float ar[8] = {a0.x, a0.y, a0.z, a0.w, a1.x, a1.y, a1.z, a1.w};
        float br[8] = {b0.x, b0.y, b0.z, b0.w, b1.x, b1.y, b1.z, b1.w};
#pragma unroll
        for (int i = 0; i < 8; ++i)
#pragma unroll
            for (int j = 0; j < 8; ++j)
                acc[i][j] += ar[i] * br[j];
    }

    float4 blo = *(const float4*)&bias[cl];
    float4 bhi = *(const float4*)&bias[chh];
    float bb[8] = {blo.x, blo.y, blo.z, blo.w, bhi.x, bhi.y, bhi.z, bhi.w};
#pragma unroll
    for (int i = 0; i < 8; ++i) {
        unsigned* rowp = bevf + (size_t)posArr[i] * 64;
        uint2 lo, hi;
        lo.x = pack2(acc[i][0] + bb[0], acc[i][1] + bb[1]);   // ch 4tc, 4tc+1
        lo.y = pack2(acc[i][2] + bb[2], acc[i][3] + bb[3]);   // ch 4tc+2, 4tc+3
        hi.x = pack2(acc[i][4] + bb[4], acc[i][5] + bb[5]);   // ch 64+4tc..
        hi.y = pack2(acc[i][6] + bb[6], acc[i][7] + bb[7]);
        ((uint2*)rowp)[tc]      = lo;    // dwords 2tc, 2tc+1
        ((uint2*)rowp)[16 + tc] = hi;    // dwords 32+2tc, 32+2tc+1
    }
}

// ---------------- pass 5: per-(row, channel-half) reduction -> 1KB-contiguous BCHW writes ----------------
// Block = (seg = b*HH+h, chalf). 512 threads, 64KB LDS [256 w][64 c] fp32.
// Reads: each point contributes a contiguous 128B half-row (full cache lines).
// Writes: per channel a 1KB contiguous row; h-consecutive blocks extend the stream.
__global__ __launch_bounds__(512, 4) void reduce_kernel(
        const unsigned* __restrict__ bevf, const int* __restrict__ segstart,
        const unsigned short* __restrict__ wlist, float* __restrict__ out) {
    __shared__ float lds[256 * 64];   // 64 KiB
    int t = threadIdx.x;
    int blk = blockIdx.x;
    blk = (blk & 7) * (NSEG * 2 / 8) + (blk >> 3);   // XCD-bijective: contiguous h per XCD
    int seg   = blk >> 1;
    int chalf = blk & 1;

    float4* z4 = (float4*)lds;
#pragma unroll
    for (int i = 0; i < 8; ++i) z4[t + 512 * i] = make_float4(0.f, 0.f, 0.f, 0.f);
    __syncthreads();

    int s0 = segstart[seg], s1 = segstart[seg + 1];
    int cnt = s1 - s0;
    int wv = t >> 6;          // wave 0..7
    int l  = t & 63;
    int half = l >> 5;        // which of 2 points this half-wave handles
    int li = l & 31;          // dword index within the 128B half-row
    int jmax = (cnt + 15) >> 4;
    for (int j0 = 0; j0 < jmax; j0 += 4) {
        unsigned v[4]; int wca[4]; bool val[4];
#pragma unroll
        for (int u = 0; u < 4; ++u) {
            int p = s0 + (j0 + u) * 16 + wv * 2 + half;
            val[u] = p < s1;
            int pi = val[u] ? p : s1 - 1;
            wca[u] = wlist[pi];                                   // half-wave broadcast
            v[u] = bevf[(size_t)(pi + 1) * 64 + chalf * 32 + li]; // 128B/half-wave stream
        }
#pragma unroll
        for (int u = 0; u < 4; ++u) if (val[u]) {
            int w = wca[u];
            float f0 = __uint_as_float(v[u] << 16);          // channel-local 2*li
            float f1 = __uint_as_float(v[u] & 0xFFFF0000u);  // channel-local 2*li+1
            atomicAdd(&lds[w * 64 + swz(2 * li, w)], f0);
            atomicAdd(&lds[w * 64 + swz(2 * li + 1, w)], f1);
        }
    }
    __syncthreads();

    int b = seg >> 8, h = seg & 255;
#pragma unroll
    for (int ci = 0; ci < 8; ++ci) {
        int cloc = wv * 8 + ci;                 // 0..63
        float* op = out + ((size_t)b * OUTC + chalf * 64 + cloc) * HWD + (size_t)h * WWD;
#pragma unroll
        for (int jj = 0; jj < 4; ++jj) {
            int w = l + 64 * jj;
            op[w] = lds[w * 64 + swz(cloc, w)];   // 256B/instr, 1KB per channel row
        }
    }
}

// ---------------- fallback (ws too small): direct scattered atomics into BCHW ----------------
__global__ __launch_bounds__(256) void naive_kernel(
        const float* __restrict__ features, const float* __restrict__ kw,
        const float* __restrict__ bias,
        const int* __restrict__ bidx, const int* __restrict__ d0,
        const int* __restrict__ d1, const int* __restrict__ zi,
        float* __restrict__ out, int n) {
    long long gid = (long long)blockIdx.x * blockDim.x + threadIdx.x;
    int pid = (int)(gid >> 7);
    int c   = (int)(gid & (OUTC - 1));
    if (pid >= n) return;
    int z = zi[pid]; z = z < 0 ? 0 : (z > NZ - 1 ? NZ - 1 : z);
    const float4* fp = (const float4*)(features + (size_t)pid * INC);
    const float* wp = kw + (size_t)z * INC * OUTC + c;
    float a0 = bias[c], a1 = 0.f, a2 = 0.f, a3 = 0.f;
#pragma unroll
    for (int i = 0; i < INC / 4; ++i) {
        float4 f = fp[i];
        a0 += f.x * wp[(size_t)(4 * i + 0) * OUTC];
        a1 += f.y * wp[(size_t)(4 * i + 1) * OUTC];
        a2 += f.z * wp[(size_t)(4 * i + 2) * OUTC];
        a3 += f.w * wp[(size_t)(4 * i + 3) * OUTC];
    }
    float acc = (a0 + a1) + (a2 + a3);
    size_t oidx = ((size_t)bidx[pid] * OUTC + c) * HWD + (size_t)d0[pid] * WWD + d1[pid];
    unsafeAtomicAdd(&out[oidx], acc);
}

extern "C" void kernel_launch(void* const* d_in, const int* in_sizes, int n_in,
                              void* d_out, int out_size, void* d_ws, size_t ws_size,
                              hipStream_t stream) {
    const float* features = (const float*)d_in[0];
    const float* kw       = (const float*)d_in[1];
    const float* bias     = (const float*)d_in[2];
    const int* batch_idx  = (const int*)d_in[3];
    const int* d0_idx     = (const int*)d_in[4];
    const int* d1_idx     = (const int*)d_in[5];
    const int* z_idx      = (const int*)d_in[6];
    float* out = (float*)d_out;
    int n = in_sizes[0] / INC;   // number of points

    size_t binsElems = (size_t)n + (size_t)NZ * PPB;
    size_t bevfBytes = (binsElems + 1) * OUTC * 2;           // ~77.5 MB
    size_t metaOff   = (bevfBytes + 255) & ~(size_t)255;
    size_t metaInts  = 32 + 3 * NSEG + 16;
    size_t binsOff   = (metaOff + metaInts * 4 + 255) & ~(size_t)255;
    size_t posOff    = binsOff + binsElems * 4;
    size_t wlistOff  = posOff + binsElems * 4;
    size_t need      = wlistOff + (size_t)n * 2 + 16;

    if (ws_size >= need) {
        char* ws = (char*)d_ws;
        unsigned* bevf = (unsigned*)ws;
        int* meta     = (int*)(ws + metaOff);
        int* counts   = meta;
        int* cursors  = meta + 8;
        int* pstart   = meta + 16;
        int* seghist  = meta + 32;
        int* segcur   = meta + 32 + NSEG;
        int* segstart = meta + 32 + 2 * NSEG;
        int* bins     = (int*)(ws + binsOff);
        int* segpos   = (int*)(ws + posOff);
        unsigned short* wlist = (unsigned short*)(ws + wlistOff);

        hipMemsetAsync(meta, 0, metaInts * 4, stream);
        hipMemsetAsync(bins, 0xFF, binsElems * 4, stream);   // -1 padding
        hipMemsetAsync(segpos, 0, binsElems * 4, stream);    // padding -> dump row 0

        int gb = (n + 255) / 256;
        hist_kernel<<<gb, 256, 0, stream>>>(z_idx, batch_idx, d0_idx, counts, seghist, n);
        prefix_kernel<<<1, 256, 0, stream>>>(counts, pstart, seghist, segstart);
        scatter_kernel<<<gb, 256, 0, stream>>>(z_idx, batch_idx, d0_idx, d1_idx,
                                               pstart, cursors, segstart, segcur,
                                               bins, segpos, wlist, n);

        int nblk = (int)((binsElems + PPB - 1) / PPB) + 1;
        gemm_kernel<<<nblk, 256, 0, stream>>>(features, kw, bias, pstart, bins,
                                              segpos, bevf);

        reduce_kernel<<<NSEG * 2, 512, 0, stream>>>(bevf, segstart, wlist, out);
    } else {
        hipMemsetAsync(out, 0, (size_t)out_size * sizeof(float), stream);
        long long threads = (long long)n * OUTC;
        int gb = (int)((threads + 255) / 256);
        naive_kernel<<<gb, 256, 0, stream>>>(features, kw, bias, batch_idx, d0_idx,
                                             d1_idx, z_idx, out, n);
    }
}

// Round 8
// 200.567 us; speedup vs baseline: 2.1667x; 2.1667x over previous
//
#include <hip/hip_runtime.h>

#define PPB   128
#define NZ    8
#define INC   64
#define OUTC  128
#define NB    4
#define HH    256
#define WWD   256
#define HWD   (HH * WWD)
#define NSEG  (NB * HH)          // 1024 row segments (b*HH + h)
#define NCELL (NB * HH * WWD)    // 262144 cells (flat bev index)

__device__ __forceinline__ unsigned bf16_rne(float x) {
    unsigned u = __float_as_uint(x);
    return (u + 0x7FFFu + ((u >> 16) & 1u)) >> 16;
}
__device__ __forceinline__ unsigned pack2(float e, float o) {   // (even ch, odd ch)
    return bf16_rne(e) | (bf16_rne(o) << 16);
}

// ---------------- pass 1: z histogram + cell histogram ----------------
__global__ void hist_kernel(const int* __restrict__ z_idx, const int* __restrict__ batch_idx,
                            const int* __restrict__ d0_idx, const int* __restrict__ d1_idx,
                            int* __restrict__ counts, int* __restrict__ cellhist, int n) {
    __shared__ int lc[NZ];
    int t = threadIdx.x;
    if (t < NZ) lc[t] = 0;
    __syncthreads();
    int i = blockIdx.x * blockDim.x + t;
    if (i < n) {
        int z = z_idx[i]; z = z < 0 ? 0 : (z > NZ - 1 ? NZ - 1 : z);
        atomicAdd(&lc[z], 1);
        int cell = (batch_idx[i] * HH + d0_idx[i]) * WWD + d1_idx[i];
        atomicAdd(&cellhist[cell], 1);
    }
    __syncthreads();
    if (t < NZ && lc[t] > 0) atomicAdd(&counts[t], lc[t]);
}

// ---------------- pass 2a: z padded prefix ----------------
__global__ void prefix_z_kernel(const int* __restrict__ counts, int* __restrict__ pstart) {
    if (threadIdx.x == 0 && blockIdx.x == 0) {
        int off = 0;
        for (int z = 0; z < NZ; ++z) {
            pstart[z] = off;
            off += ((counts[z] + PPB - 1) / PPB) * PPB;
        }
        pstart[NZ] = off;
    }
}

// ---------------- pass 2b: 3-kernel exclusive scan over 262144 cell counts ----------------
__global__ __launch_bounds__(256) void scan_local(const int* __restrict__ cellhist,
                                                  int* __restrict__ cellstart,
                                                  int* __restrict__ chunksum) {
    __shared__ int ts[256];
    int t = threadIdx.x;
    int base = blockIdx.x * 1024 + t * 4;
    int4 v = *(const int4*)&cellhist[base];
    int s = v.x + v.y + v.z + v.w;
    ts[t] = s;
    __syncthreads();
    for (int d = 1; d < 256; d <<= 1) {
        int x = (t >= d) ? ts[t - d] : 0;
        __syncthreads();
        ts[t] += x;
        __syncthreads();
    }
    int excl = ts[t] - s;
    int4 o;
    o.x = excl; o.y = excl + v.x; o.z = o.y + v.y; o.w = o.z + v.z;
    *(int4*)&cellstart[base] = o;
    if (t == 255) chunksum[blockIdx.x] = ts[255];
}

__global__ __launch_bounds__(256) void scan_top(int* __restrict__ chunksum,
                                                int* __restrict__ cellstart) {
    __shared__ int ts[256];
    int t = threadIdx.x;
    int s = chunksum[t];
    ts[t] = s;
    __syncthreads();
    for (int d = 1; d < 256; d <<= 1) {
        int x = (t >= d) ? ts[t - d] : 0;
        __syncthreads();
        ts[t] += x;
        __syncthreads();
    }
    chunksum[t] = ts[t] - s;                     // exclusive chunk offsets
    if (t == 255) cellstart[NCELL] = ts[255];    // grand total
}

__global__ __launch_bounds__(256) void scan_add(int* __restrict__ cellstart,
                                                const int* __restrict__ chunksum) {
    int off = chunksum[blockIdx.x];
    if (off == 0) return;
    int base = blockIdx.x * 1024 + threadIdx.x * 4;
    int4 v = *(int4*)&cellstart[base];
    v.x += off; v.y += off; v.z += off; v.w += off;
    *(int4*)&cellstart[base] = v;
}

// ---------------- pass 3: scatter ids into z bins + cell-sorted positions ----------------
__global__ void scatter_kernel(const int* __restrict__ z_idx, const int* __restrict__ batch_idx,
                               const int* __restrict__ d0_idx, const int* __restrict__ d1_idx,
                               const int* __restrict__ pstart, int* __restrict__ cursors,
                               const int* __restrict__ cellstart, int* __restrict__ cellcur,
                               int* __restrict__ bins, int* __restrict__ segpos, int n) {
    __shared__ int lc[NZ];
    __shared__ int lbase[NZ];
    int t = threadIdx.x;
    if (t < NZ) lc[t] = 0;
    __syncthreads();
    int i = blockIdx.x * blockDim.x + t;
    int z = 0, rank = 0;
    bool valid = (i < n);
    if (valid) {
        z = z_idx[i]; z = z < 0 ? 0 : (z > NZ - 1 ? NZ - 1 : z);
        rank = atomicAdd(&lc[z], 1);
    }
    __syncthreads();
    if (t < NZ) lbase[t] = (lc[t] > 0) ? atomicAdd(&cursors[t], lc[t]) : 0;
    __syncthreads();
    if (valid) {
        int slot = pstart[z] + lbase[z] + rank;
        bins[slot] = i;
        int cell = (batch_idx[i] * HH + d0_idx[i]) * WWD + d1_idx[i];
        int r2 = atomicAdd(&cellcur[cell], 1);
        segpos[slot] = 1 + cellstart[cell] + r2;   // row 0 of bevf = dump for padding
    }
}

// ---------------- pass 4: LDS-tiled fp32 GEMM per z-bin -> bf16 rows at cell-sorted pos ----------------
// Row layout: dword d packs channels (2d, 2d+1). Thread tc owns channels 8tc..8tc+7
// -> one 16B store per point per thread (full 256B line per 16-thread group).
__global__ __launch_bounds__(256) void gemm_kernel(
        const float* __restrict__ features, const float* __restrict__ kw,
        const float* __restrict__ bias,
        const int* __restrict__ pstart, const int* __restrict__ bins,
        const int* __restrict__ segpos, unsigned* __restrict__ bevf) {
    __shared__ __align__(16) float A[INC][PPB];     // 32 KiB, [k][p]
    __shared__ __align__(16) float Wl[INC][OUTC];   // 32 KiB, [k][c]

    int start = blockIdx.x * PPB;
    int total = pstart[NZ];
    if (start >= total) return;
    int z = 0;
#pragma unroll
    for (int zz = 1; zz < NZ; ++zz)
        if (start >= pstart[zz]) z = zz;

    int tid = threadIdx.x;
    int tc = tid & 15;
    int tp = tid >> 4;
    int p0 = tp * 8;

    int posArr[8];
#pragma unroll
    for (int i = 0; i < 8; ++i) posArr[i] = segpos[start + p0 + i];

    {   // stage W[z]: straight 32KB copy
        const float4* src = (const float4*)(kw + (size_t)z * INC * OUTC);
        float4* dst = (float4*)&Wl[0][0];
#pragma unroll
        for (int i = 0; i < 8; ++i) dst[tid + 256 * i] = src[tid + 256 * i];
    }
    {   // stage A: gather 128 feature rows, write transposed [k][p]
        int r = tid >> 1;
        int half = tid & 1;
        int raw = bins[start + r];
        int nid = raw < 0 ? 0 : raw;
        const float4* fp = (const float4*)(features + (size_t)nid * INC) + half * 8;
#pragma unroll
        for (int q = 0; q < 8; ++q) {
            float4 f = fp[q];
            int k = half * 32 + q * 4;
            A[k + 0][r] = f.x; A[k + 1][r] = f.y; A[k + 2][r] = f.z; A[k + 3][r] = f.w;
        }
    }
    __syncthreads();

    int c0 = tc * 8;   // channels c0..c0+7

    float acc[8][8];
#pragma unroll
    for (int i = 0; i < 8; ++i)
#pragma unroll
        for (int j = 0; j < 8; ++j) acc[i][j] = 0.f;

#pragma unroll 4
    for (int k = 0; k < INC; ++k) {
        float4 b0 = *(const float4*)&Wl[k][c0];
        float4 b1 = *(const float4*)&Wl[k][c0 + 4];
        float4 a0 = *(const float4*)&A[k][p0];
        float4 a1 = *(const float4*)&A[k][p0 + 4];
        float ar[8] = {a0.x, a0.y, a0.z, a0.w, a1.x, a1.y, a1.z, a1.w};
        float br[8] = {b0.x, b0.y, b0.z, b0.w, b1.x, b1.y, b1.z, b1.w};
#pragma unroll
        for (int i = 0; i < 8; ++i)
#pragma unroll
            for (int j = 0; j < 8; ++j)
                acc[i][j] += ar[i] * br[j];
    }

    float4 blo = *(const float4*)&bias[c0];
    float4 bhi = *(const float4*)&bias[c0 + 4];
    float bb[8] = {blo.x, blo.y, blo.z, blo.w, bhi.x, bhi.y, bhi.z, bhi.w};
#pragma unroll
    for (int i = 0; i < 8; ++i) {
        unsigned* rowp = bevf + (size_t)posArr[i] * 64;
        uint4 pk;
        pk.x = pack2(acc[i][0] + bb[0], acc[i][1] + bb[1]);   // dwords 4tc..4tc+3
        pk.y = pack2(acc[i][2] + bb[2], acc[i][3] + bb[3]);
        pk.z = pack2(acc[i][4] + bb[4], acc[i][5] + bb[5]);
        pk.w = pack2(acc[i][6] + bb[6], acc[i][7] + bb[7]);
        ((uint4*)rowp)[tc] = pk;   // 16 lanes x 16B = 256B full-line store per point
    }
}

// ---------------- pass 5: register-accumulating per-row reduction (ZERO atomics) ----------------
// Block = row segment (b,h); wave wv owns cells wv*32..wv*32+31 (contiguous bevf ranges);
// lane l = dword l (channels 2l, 2l+1). Cells are pre-sorted -> contiguous rows per cell,
// register fp32 accumulate, one plain swizzled LDS write per (cell, dword), then the
// streaming BCHW writeout (1KB contiguous per channel, XCD-contiguous h ranges).
__global__ __launch_bounds__(512) void reduce_kernel(
        const unsigned* __restrict__ bevf, const int* __restrict__ cellstart,
        float* __restrict__ out) {
    __shared__ unsigned tile[256 * 64];   // 64 KiB, [w][dword] rotate-swizzled by w
    int t = threadIdx.x;
    int blk = blockIdx.x;
    blk = (blk & 7) * (NSEG / 8) + (blk >> 3);   // XCD-contiguous segments
    int seg = blk;
    int wv = t >> 6, l = t & 63;

    int cell0 = seg * WWD + wv * 32;
    int cs_n = cellstart[cell0];
    int ce_n = cellstart[cell0 + 1];
    for (int j = 0; j < 32; ++j) {
        int cs = cs_n, ce = ce_n;
        cs_n = ce;                                     // next cell starts where this ends
        if (j < 31) ce_n = cellstart[cell0 + j + 2];   // scalar prefetch
        float f0 = 0.f, f1 = 0.f;
        int k = cs;
        for (; k + 1 < ce; k += 2) {                   // 2 loads in flight
            unsigned v0 = bevf[(size_t)(k + 1) * 64 + l];
            unsigned v1 = bevf[(size_t)(k + 2) * 64 + l];
            f0 += __uint_as_float(v0 << 16);
            f1 += __uint_as_float(v0 & 0xFFFF0000u);
            f0 += __uint_as_float(v1 << 16);
            f1 += __uint_as_float(v1 & 0xFFFF0000u);
        }
        if (k < ce) {
            unsigned v0 = bevf[(size_t)(k + 1) * 64 + l];
            f0 += __uint_as_float(v0 << 16);
            f1 += __uint_as_float(v0 & 0xFFFF0000u);
        }
        int w = wv * 32 + j;
        tile[w * 64 + ((l + w) & 63)] = pack2(f0, f1);   // plain write, 2-way max (free)
    }
    __syncthreads();

    int b = seg >> 8, h = seg & 255;
    float* ob = out + (size_t)b * OUTC * HWD + (size_t)h * WWD;
#pragma unroll
    for (int r = 0; r < 16; ++r) {
        int c = wv + 8 * r;
        int d = c >> 1;
        float* op = ob + (size_t)c * HWD;
#pragma unroll
        for (int q = 0; q < 4; ++q) {
            int w = 64 * q + l;
            unsigned v = tile[w * 64 + ((d + w) & 63)];
            op[w] = __uint_as_float((c & 1) ? (v & 0xFFFF0000u) : (v << 16));
        }
    }
}

// ---------------- fallback (ws too small): direct scattered atomics into BCHW ----------------
__global__ __launch_bounds__(256) void naive_kernel(
        const float* __restrict__ features, const float* __restrict__ kw,
        const float* __restrict__ bias,
        const int* __restrict__ bidx, const int* __restrict__ d0,
        const int* __restrict__ d1, const int* __restrict__ zi,
        float* __restrict__ out, int n) {
    long long gid = (long long)blockIdx.x * blockDim.x + threadIdx.x;
    int pid = (int)(gid >> 7);
    int c   = (int)(gid & (OUTC - 1));
    if (pid >= n) return;
    int z = zi[pid]; z = z < 0 ? 0 : (z > NZ - 1 ? NZ - 1 : z);
    const float4* fp = (const float4*)(features + (size_t)pid * INC);
    const float* wp = kw + (size_t)z * INC * OUTC + c;
    float a0 = bias[c], a1 = 0.f, a2 = 0.f, a3 = 0.f;
#pragma unroll
    for (int i = 0; i < INC / 4; ++i) {
        float4 f = fp[i];
        a0 += f.x * wp[(size_t)(4 * i + 0) * OUTC];
        a1 += f.y * wp[(size_t)(4 * i + 1) * OUTC];
        a2 += f.z * wp[(size_t)(4 * i + 2) * OUTC];
        a3 += f.w * wp[(size_t)(4 * i + 3) * OUTC];
    }
    float acc = (a0 + a1) + (a2 + a3);
    size_t oidx = ((size_t)bidx[pid] * OUTC + c) * HWD + (size_t)d0[pid] * WWD + d1[pid];
    unsafeAtomicAdd(&out[oidx], acc);
}

extern "C" void kernel_launch(void* const* d_in, const int* in_sizes, int n_in,
                              void* d_out, int out_size, void* d_ws, size_t ws_size,
                              hipStream_t stream) {
    const float* features = (const float*)d_in[0];
    const float* kw       = (const float*)d_in[1];
    const float* bias     = (const float*)d_in[2];
    const int* batch_idx  = (const int*)d_in[3];
    const int* d0_idx     = (const int*)d_in[4];
    const int* d1_idx     = (const int*)d_in[5];
    const int* z_idx      = (const int*)d_in[6];
    float* out = (float*)d_out;
    int n = in_sizes[0] / INC;   // number of points

    size_t binsElems = (size_t)n + (size_t)NZ * PPB;
    size_t bevfBytes = (binsElems + 1) * OUTC * 2;           // ~77.5 MB
    size_t metaOff   = (bevfBytes + 255) & ~(size_t)255;
    size_t chOff     = metaOff + 32 * 4;                     // cellhist
    size_t ccOff     = chOff + (size_t)NCELL * 4;            // cellcur
    size_t csOff     = ccOff + (size_t)NCELL * 4;            // cellstart (NCELL+1)
    size_t ckOff     = csOff + (size_t)(NCELL + 4) * 4;      // chunksum (256)
    size_t binsOff   = (ckOff + 256 * 4 + 255) & ~(size_t)255;
    size_t posOff    = binsOff + binsElems * 4;
    size_t need      = posOff + binsElems * 4 + 16;

    if (ws_size >= need) {
        char* ws = (char*)d_ws;
        unsigned* bevf = (unsigned*)ws;
        int* meta      = (int*)(ws + metaOff);   // counts[8], cursors[8], pstart[9]
        int* counts    = meta;
        int* cursors   = meta + 8;
        int* pstart    = meta + 16;
        int* cellhist  = (int*)(ws + chOff);
        int* cellcur   = (int*)(ws + ccOff);
        int* cellstart = (int*)(ws + csOff);
        int* chunksum  = (int*)(ws + ckOff);
        int* bins      = (int*)(ws + binsOff);
        int* segpos    = (int*)(ws + posOff);

        hipMemsetAsync(meta, 0, 32 * 4, stream);
        hipMemsetAsync(cellhist, 0, (size_t)NCELL * 4, stream);
        hipMemsetAsync(cellcur, 0, (size_t)NCELL * 4, stream);
        hipMemsetAsync(bins, 0xFF, binsElems * 4, stream);   // -1 padding
        hipMemsetAsync(segpos, 0, binsElems * 4, stream);    // padding -> dump row 0

        int gb = (n + 255) / 256;
        hist_kernel<<<gb, 256, 0, stream>>>(z_idx, batch_idx, d0_idx, d1_idx,
                                            counts, cellhist, n);
        prefix_z_kernel<<<1, 64, 0, stream>>>(counts, pstart);
        scan_local<<<256, 256, 0, stream>>>(cellhist, cellstart, chunksum);
        scan_top<<<1, 256, 0, stream>>>(chunksum, cellstart);
        scan_add<<<256, 256, 0, stream>>>(cellstart, chunksum);
        scatter_kernel<<<gb, 256, 0, stream>>>(z_idx, batch_idx, d0_idx, d1_idx,
                                               pstart, cursors, cellstart, cellcur,
                                               bins, segpos, n);

        int nblk = (int)((binsElems + PPB - 1) / PPB) + 1;
        gemm_kernel<<<nblk, 256, 0, stream>>>(features, kw, bias, pstart, bins,
                                              segpos, bevf);

        reduce_kernel<<<NSEG, 512, 0, stream>>>(bevf, cellstart, out);
    } else {
        hipMemsetAsync(out, 0, (size_t)out_size * sizeof(float), stream);
        long long threads = (long long)n * OUTC;
        int gb = (int)((threads + 255) / 256);
        naive_kernel<<<gb, 256, 0, stream>>>(features, kw, bias, batch_idx, d0_idx,
                                             d1_idx, z_idx, out, n);
    }
}

// Round 9
// 197.229 us; speedup vs baseline: 2.2034x; 1.0169x over previous
//
#include <hip/hip_runtime.h>

#define PPB   128
#define NZ    8
#define INC   64
#define OUTC  128
#define NB    4
#define HH    256
#define WWD   256
#define HWD   (HH * WWD)
#define NSEG  (NB * HH)          // 1024 row segments (b*HH + h)
#define NCELL (NB * HH * WWD)    // 262144 cells (flat bev index)

__device__ __forceinline__ unsigned bf16_rne(float x) {
    unsigned u = __float_as_uint(x);
    return (u + 0x7FFFu + ((u >> 16) & 1u)) >> 16;
}
__device__ __forceinline__ unsigned pack2(float lo, float hi) {   // (ch d, ch d+64)
    return bf16_rne(lo) | (bf16_rne(hi) << 16);
}

// ---------------- pass 1: z histogram + cell histogram ----------------
__global__ void hist_kernel(const int* __restrict__ z_idx, const int* __restrict__ batch_idx,
                            const int* __restrict__ d0_idx, const int* __restrict__ d1_idx,
                            int* __restrict__ counts, int* __restrict__ cellhist, int n) {
    __shared__ int lc[NZ];
    int t = threadIdx.x;
    if (t < NZ) lc[t] = 0;
    __syncthreads();
    int i = blockIdx.x * blockDim.x + t;
    if (i < n) {
        int z = z_idx[i]; z = z < 0 ? 0 : (z > NZ - 1 ? NZ - 1 : z);
        atomicAdd(&lc[z], 1);
        int cell = (batch_idx[i] * HH + d0_idx[i]) * WWD + d1_idx[i];
        atomicAdd(&cellhist[cell], 1);
    }
    __syncthreads();
    if (t < NZ && lc[t] > 0) atomicAdd(&counts[t], lc[t]);
}

// ---------------- pass 2a: z padded prefix ----------------
__global__ void prefix_z_kernel(const int* __restrict__ counts, int* __restrict__ pstart) {
    if (threadIdx.x == 0 && blockIdx.x == 0) {
        int off = 0;
        for (int z = 0; z < NZ; ++z) {
            pstart[z] = off;
            off += ((counts[z] + PPB - 1) / PPB) * PPB;
        }
        pstart[NZ] = off;
    }
}

// ---------------- pass 2b: 3-kernel exclusive scan over 262144 cell counts ----------------
__global__ __launch_bounds__(256) void scan_local(const int* __restrict__ cellhist,
                                                  int* __restrict__ cellstart,
                                                  int* __restrict__ chunksum) {
    __shared__ int ts[256];
    int t = threadIdx.x;
    int base = blockIdx.x * 1024 + t * 4;
    int4 v = *(const int4*)&cellhist[base];
    int s = v.x + v.y + v.z + v.w;
    ts[t] = s;
    __syncthreads();
    for (int d = 1; d < 256; d <<= 1) {
        int x = (t >= d) ? ts[t - d] : 0;
        __syncthreads();
        ts[t] += x;
        __syncthreads();
    }
    int excl = ts[t] - s;
    int4 o;
    o.x = excl; o.y = excl + v.x; o.z = o.y + v.y; o.w = o.z + v.z;
    *(int4*)&cellstart[base] = o;
    if (t == 255) chunksum[blockIdx.x] = ts[255];
}

__global__ __launch_bounds__(256) void scan_top(int* __restrict__ chunksum,
                                                int* __restrict__ cellstart) {
    __shared__ int ts[256];
    int t = threadIdx.x;
    int s = chunksum[t];
    ts[t] = s;
    __syncthreads();
    for (int d = 1; d < 256; d <<= 1) {
        int x = (t >= d) ? ts[t - d] : 0;
        __syncthreads();
        ts[t] += x;
        __syncthreads();
    }
    chunksum[t] = ts[t] - s;                     // exclusive chunk offsets
    if (t == 255) cellstart[NCELL] = ts[255];    // grand total
}

__global__ __launch_bounds__(256) void scan_add(int* __restrict__ cellstart,
                                                const int* __restrict__ chunksum) {
    int off = chunksum[blockIdx.x];
    if (off == 0) return;
    int base = blockIdx.x * 1024 + threadIdx.x * 4;
    int4 v = *(int4*)&cellstart[base];
    v.x += off; v.y += off; v.z += off; v.w += off;
    *(int4*)&cellstart[base] = v;
}

// ---------------- pass 3: scatter ids into z bins + cell-sorted positions ----------------
__global__ void scatter_kernel(const int* __restrict__ z_idx, const int* __restrict__ batch_idx,
                               const int* __restrict__ d0_idx, const int* __restrict__ d1_idx,
                               const int* __restrict__ pstart, int* __restrict__ cursors,
                               const int* __restrict__ cellstart, int* __restrict__ cellcur,
                               int* __restrict__ bins, int* __restrict__ segpos, int n) {
    __shared__ int lc[NZ];
    __shared__ int lbase[NZ];
    int t = threadIdx.x;
    if (t < NZ) lc[t] = 0;
    __syncthreads();
    int i = blockIdx.x * blockDim.x + t;
    int z = 0, rank = 0;
    bool valid = (i < n);
    if (valid) {
        z = z_idx[i]; z = z < 0 ? 0 : (z > NZ - 1 ? NZ - 1 : z);
        rank = atomicAdd(&lc[z], 1);
    }
    __syncthreads();
    if (t < NZ) lbase[t] = (lc[t] > 0) ? atomicAdd(&cursors[t], lc[t]) : 0;
    __syncthreads();
    if (valid) {
        int slot = pstart[z] + lbase[z] + rank;
        bins[slot] = i;
        int cell = (batch_idx[i] * HH + d0_idx[i]) * WWD + d1_idx[i];
        int r2 = atomicAdd(&cellcur[cell], 1);
        segpos[slot] = 1 + cellstart[cell] + r2;   // row 0 of bevf = dump for padding
    }
}

// ---------------- pass 4: LDS-tiled fp32 GEMM per z-bin -> bf16 rows at cell-sorted pos ----------------
// Row layout: dword d packs channels (d, d+64). Thread tc owns channels {4tc..+3, 64+4tc..+3}
// -> Wl reads at chunks tc and 16+tc (2-way bank alias = free), packed dwords 4tc..4tc+3
// contiguous -> one 16B store per point per thread (full 256B line per 16-thread group).
__global__ __launch_bounds__(256) void gemm_kernel(
        const float* __restrict__ features, const float* __restrict__ kw,
        const float* __restrict__ bias,
        const int* __restrict__ pstart, const int* __restrict__ bins,
        const int* __restrict__ segpos, unsigned* __restrict__ bevf) {
    __shared__ __align__(16) float A[INC][PPB];     // 32 KiB, [k][p]
    __shared__ __align__(16) float Wl[INC][OUTC];   // 32 KiB, [k][c]

    int start = blockIdx.x * PPB;
    int total = pstart[NZ];
    if (start >= total) return;
    int z = 0;
#pragma unroll
    for (int zz = 1; zz < NZ; ++zz)
        if (start >= pstart[zz]) z = zz;

    int tid = threadIdx.x;
    int tc = tid & 15;
    int tp = tid >> 4;
    int p0 = tp * 8;

    int posArr[8];
#pragma unroll
    for (int i = 0; i < 8; ++i) posArr[i] = segpos[start + p0 + i];

    {   // stage W[z]: straight 32KB copy
        const float4* src = (const float4*)(kw + (size_t)z * INC * OUTC);
        float4* dst = (float4*)&Wl[0][0];
#pragma unroll
        for (int i = 0; i < 8; ++i) dst[tid + 256 * i] = src[tid + 256 * i];
    }
    {   // stage A: gather 128 feature rows, write transposed [k][p]
        int r = tid >> 1;
        int half = tid & 1;
        int raw = bins[start + r];
        int nid = raw < 0 ? 0 : raw;
        const float4* fp = (const float4*)(features + (size_t)nid * INC) + half * 8;
#pragma unroll
        for (int q = 0; q < 8; ++q) {
            float4 f = fp[q];
            int k = half * 32 + q * 4;
            A[k + 0][r] = f.x; A[k + 1][r] = f.y; A[k + 2][r] = f.z; A[k + 3][r] = f.w;
        }
    }
    __syncthreads();

    int cl  = tc * 4;        // channels cl..cl+3
    int chh = 64 + tc * 4;   // channels chh..chh+3

    float acc[8][8];
#pragma unroll
    for (int i = 0; i < 8; ++i)
#pragma unroll
        for (int j = 0; j < 8; ++j) acc[i][j] = 0.f;

#pragma unroll 4
    for (int k = 0; k < INC; ++k) {
        float4 b0 = *(const float4*)&Wl[k][cl];      // chunk tc      (2-way, free)
        float4 b1 = *(const float4*)&Wl[k][chh];     // chunk 16+tc   (2-way, free)
        float4 a0 = *(const float4*)&A[k][p0];
        float4 a1 = *(const float4*)&A[k][p0 + 4];
        float ar[8] = {a0.x, a0.y, a0.z, a0.w, a1.x, a1.y, a1.z, a1.w};
        float br[8] = {b0.x, b0.y, b0.z, b0.w, b1.x, b1.y, b1.z, b1.w};
#pragma unroll
        for (int i = 0; i < 8; ++i)
#pragma unroll
            for (int j = 0; j < 8; ++j)
                acc[i][j] += ar[i] * br[j];
    }

    float4 blo = *(const float4*)&bias[cl];
    float4 bhi = *(const float4*)&bias[chh];
    float bb[8] = {blo.x, blo.y, blo.z, blo.w, bhi.x, bhi.y, bhi.z, bhi.w};
#pragma unroll
    for (int i = 0; i < 8; ++i) {
        unsigned* rowp = bevf + (size_t)posArr[i] * 64;
        uint4 pk;   // dwords 4tc..4tc+3, dword d = (ch d, ch d+64)
        pk.x = pack2(acc[i][0] + bb[0], acc[i][4] + bb[4]);
        pk.y = pack2(acc[i][1] + bb[1], acc[i][5] + bb[5]);
        pk.z = pack2(acc[i][2] + bb[2], acc[i][6] + bb[6]);
        pk.w = pack2(acc[i][3] + bb[3], acc[i][7] + bb[7]);
        ((uint4*)rowp)[tc] = pk;   // 16 lanes x 16B = 256B full-line store per point
    }
}

// ---------------- pass 5: register-accumulating per-row reduction (ZERO atomics) ----------------
// Block = row segment (b,h); wave wv owns cells wv*32..wv*32+31 (contiguous bevf ranges);
// lane l = dword l = channels (l, l+64). Cells pre-sorted -> contiguous rows per cell,
// register fp32 accumulate, one plain swizzled LDS write per (cell, dword), then the
// streaming BCHW writeout (1KB contiguous per channel, XCD-contiguous h ranges).
__global__ __launch_bounds__(512) void reduce_kernel(
        const unsigned* __restrict__ bevf, const int* __restrict__ cellstart,
        float* __restrict__ out) {
    __shared__ unsigned tile[256 * 64];   // 64 KiB, [w][dword] rotate-swizzled by w
    int t = threadIdx.x;
    int blk = blockIdx.x;
    blk = (blk & 7) * (NSEG / 8) + (blk >> 3);   // XCD-contiguous segments
    int seg = blk;
    int wv = t >> 6, l = t & 63;

    int cell0 = seg * WWD + wv * 32;
    int cs_n = cellstart[cell0];
    int ce_n = cellstart[cell0 + 1];
    for (int j = 0; j < 32; ++j) {
        int cs = cs_n, ce = ce_n;
        cs_n = ce;                                     // next cell starts where this ends
        if (j < 31) ce_n = cellstart[cell0 + j + 2];   // scalar prefetch
        float f0 = 0.f, f1 = 0.f;
        int k = cs;
        for (; k + 1 < ce; k += 2) {                   // 2 loads in flight
            unsigned v0 = bevf[(size_t)(k + 1) * 64 + l];
            unsigned v1 = bevf[(size_t)(k + 2) * 64 + l];
            f0 += __uint_as_float(v0 << 16);
            f1 += __uint_as_float(v0 & 0xFFFF0000u);
            f0 += __uint_as_float(v1 << 16);
            f1 += __uint_as_float(v1 & 0xFFFF0000u);
        }
        if (k < ce) {
            unsigned v0 = bevf[(size_t)(k + 1) * 64 + l];
            f0 += __uint_as_float(v0 << 16);
            f1 += __uint_as_float(v0 & 0xFFFF0000u);
        }
        int w = wv * 32 + j;
        tile[w * 64 + ((l + w) & 63)] = pack2(f0, f1);   // plain write, 2-way max (free)
    }
    __syncthreads();

    int b = seg >> 8, h = seg & 255;
    float* ob = out + (size_t)b * OUTC * HWD + (size_t)h * WWD;
#pragma unroll
    for (int r = 0; r < 16; ++r) {
        int c = wv + 8 * r;        // 0..127
        int d = c & 63;            // dword index
        float* op = ob + (size_t)c * HWD;
#pragma unroll
        for (int q = 0; q < 4; ++q) {
            int w = 64 * q + l;
            unsigned v = tile[w * 64 + ((d + w) & 63)];
            op[w] = __uint_as_float((c >> 6) ? (v & 0xFFFF0000u) : (v << 16));
        }
    }
}

// ---------------- fallback (ws too small): direct scattered atomics into BCHW ----------------
__global__ __launch_bounds__(256) void naive_kernel(
        const float* __restrict__ features, const float* __restrict__ kw,
        const float* __restrict__ bias,
        const int* __restrict__ bidx, const int* __restrict__ d0,
        const int* __restrict__ d1, const int* __restrict__ zi,
        float* __restrict__ out, int n) {
    long long gid = (long long)blockIdx.x * blockDim.x + threadIdx.x;
    int pid = (int)(gid >> 7);
    int c   = (int)(gid & (OUTC - 1));
    if (pid >= n) return;
    int z = zi[pid]; z = z < 0 ? 0 : (z > NZ - 1 ? NZ - 1 : z);
    const float4* fp = (const float4*)(features + (size_t)pid * INC);
    const float* wp = kw + (size_t)z * INC * OUTC + c;
    float a0 = bias[c], a1 = 0.f, a2 = 0.f, a3 = 0.f;
#pragma unroll
    for (int i = 0; i < INC / 4; ++i) {
        float4 f = fp[i];
        a0 += f.x * wp[(size_t)(4 * i + 0) * OUTC];
        a1 += f.y * wp[(size_t)(4 * i + 1) * OUTC];
        a2 += f.z * wp[(size_t)(4 * i + 2) * OUTC];
        a3 += f.w * wp[(size_t)(4 * i + 3) * OUTC];
    }
    float acc = (a0 + a1) + (a2 + a3);
    size_t oidx = ((size_t)bidx[pid] * OUTC + c) * HWD + (size_t)d0[pid] * WWD + d1[pid];
    unsafeAtomicAdd(&out[oidx], acc);
}

extern "C" void kernel_launch(void* const* d_in, const int* in_sizes, int n_in,
                              void* d_out, int out_size, void* d_ws, size_t ws_size,
                              hipStream_t stream) {
    const float* features = (const float*)d_in[0];
    const float* kw       = (const float*)d_in[1];
    const float* bias     = (const float*)d_in[2];
    const int* batch_idx  = (const int*)d_in[3];
    const int* d0_idx     = (const int*)d_in[4];
    const int* d1_idx     = (const int*)d_in[5];
    const int* z_idx      = (const int*)d_in[6];
    float* out = (float*)d_out;
    int n = in_sizes[0] / INC;   // number of points

    size_t binsElems = (size_t)n + (size_t)NZ * PPB;
    size_t bevfBytes = (binsElems + 1) * OUTC * 2;           // ~77.5 MB
    size_t metaOff   = (bevfBytes + 255) & ~(size_t)255;
    size_t chOff     = metaOff + 32 * 4;                     // cellhist
    size_t ccOff     = chOff + (size_t)NCELL * 4;            // cellcur
    size_t csOff     = ccOff + (size_t)NCELL * 4;            // cellstart (NCELL+1)
    size_t ckOff     = csOff + (size_t)(NCELL + 4) * 4;      // chunksum (256)
    size_t binsOff   = (ckOff + 256 * 4 + 255) & ~(size_t)255;
    size_t posOff    = binsOff + binsElems * 4;
    size_t need      = posOff + binsElems * 4 + 16;

    if (ws_size >= need) {
        char* ws = (char*)d_ws;
        unsigned* bevf = (unsigned*)ws;
        int* meta      = (int*)(ws + metaOff);   // counts[8], cursors[8], pstart[9]
        int* counts    = meta;
        int* cursors   = meta + 8;
        int* pstart    = meta + 16;
        int* cellhist  = (int*)(ws + chOff);
        int* cellcur   = (int*)(ws + ccOff);
        int* cellstart = (int*)(ws + csOff);
        int* chunksum  = (int*)(ws + ckOff);
        int* bins      = (int*)(ws + binsOff);
        int* segpos    = (int*)(ws + posOff);

        hipMemsetAsync(meta, 0, 32 * 4, stream);
        hipMemsetAsync(cellhist, 0, (size_t)NCELL * 4, stream);
        hipMemsetAsync(cellcur, 0, (size_t)NCELL * 4, stream);
        hipMemsetAsync(bins, 0xFF, binsElems * 4, stream);   // -1 padding
        hipMemsetAsync(segpos, 0, binsElems * 4, stream);    // padding -> dump row 0

        int gb = (n + 255) / 256;
        hist_kernel<<<gb, 256, 0, stream>>>(z_idx, batch_idx, d0_idx, d1_idx,
                                            counts, cellhist, n);
        prefix_z_kernel<<<1, 64, 0, stream>>>(counts, pstart);
        scan_local<<<256, 256, 0, stream>>>(cellhist, cellstart, chunksum);
        scan_top<<<1, 256, 0, stream>>>(chunksum, cellstart);
        scan_add<<<256, 256, 0, stream>>>(cellstart, chunksum);
        scatter_kernel<<<gb, 256, 0, stream>>>(z_idx, batch_idx, d0_idx, d1_idx,
                                               pstart, cursors, cellstart, cellcur,
                                               bins, segpos, n);

        int nblk = (int)((binsElems + PPB - 1) / PPB) + 1;
        gemm_kernel<<<nblk, 256, 0, stream>>>(features, kw, bias, pstart, bins,
                                              segpos, bevf);

        reduce_kernel<<<NSEG, 512, 0, stream>>>(bevf, cellstart, out);
    } else {
        hipMemsetAsync(out, 0, (size_t)out_size * sizeof(float), stream);
        long long threads = (long long)n * OUTC;
        int gb = (int)((threads + 255) / 256);
        naive_kernel<<<gb, 256, 0, stream>>>(features, kw, bias, batch_idx, d0_idx,
                                             d1_idx, z_idx, out, n);
    }
}